// Round 2
// baseline (243.912 us; speedup 1.0000x reference)
//
#include <hip/hip_runtime.h>

#define B_N 256
#define C_N 50000
#define D_N 512
#define ALPHA 0.5f

// Kernel 1: recover labels from one-hot rows + per-class counts.
// 3.2M float4s; each thread handles 4 coalesced float4s (issued back-to-back
// for memory-level parallelism). 3125 blocks x 256 threads.
__global__ __launch_bounds__(256) void find_labels(
        const float* __restrict__ onehot,
        int* __restrict__ labels,
        int* __restrict__ counts) {
    int t = threadIdx.x;
    int base = blockIdx.x * 1024 + t;                   // float4 index of k=0
    const float4* p = (const float4*)onehot;
    float4 v[4];
#pragma unroll
    for (int k = 0; k < 4; ++k) v[k] = p[base + k * 256];   // 4 independent loads
#pragma unroll
    for (int k = 0; k < 4; ++k) {
        float4 q = v[k];
        if (q.x != 0.f || q.y != 0.f || q.z != 0.f || q.w != 0.f) {
            int g = (base + k * 256) * 4;
            float f[4] = {q.x, q.y, q.z, q.w};
#pragma unroll
            for (int j = 0; j < 4; ++j) {
                if (f[j] != 0.f) {
                    int gg = g + j;
                    int b = gg / C_N;
                    int c = gg - b * C_N;
                    labels[b] = c;                      // exactly one writer per b
                    atomicAdd(&counts[c], 1);
                }
            }
        }
    }
}

// Kernel 2: result[b] = sum_d (x[b][d] - centers[label_b][d])^2
__global__ __launch_bounds__(128) void sq_dist(
        const float* __restrict__ x,
        const float* __restrict__ centers,
        const int* __restrict__ labels,
        float* __restrict__ result) {
    int b = blockIdx.x;
    int t = threadIdx.x;                                // 0..127
    int lab = labels[b];
    float4 xv = ((const float4*)(x + (size_t)b * D_N))[t];
    float4 cv = ((const float4*)(centers + (size_t)lab * D_N))[t];
    float dx = xv.x - cv.x, dy = xv.y - cv.y, dz = xv.z - cv.z, dw = xv.w - cv.w;
    float s = dx * dx + dy * dy + dz * dz + dw * dw;
#pragma unroll
    for (int off = 32; off > 0; off >>= 1) s += __shfl_down(s, off, 64);
    __shared__ float ws[2];
    if ((t & 63) == 0) ws[t >> 6] = s;
    __syncthreads();
    if (t == 0) result[b] = ws[0] + ws[1];
}

// Kernel 3: new_centers row update, grid-stride. Each 256-thread block
// processes 8 rows per iteration: threads split as (half = t>>7) picking
// row parity, (tt = t&127) the float4 within the row. 4 independent loads
// per thread are issued before any use -> deep MLP, few fat blocks instead
// of 50000 one-load blocks (which was dispatch/latency-bound at 2.5 TB/s).
//   new[c] = centers[c]*(1 - a*n/(n+1)) + (a/(n+1)) * sum_{label_b=c} x[b]
__global__ __launch_bounds__(256) void update_centers(
        const float* __restrict__ x,
        const float* __restrict__ centers,
        const int* __restrict__ labels,
        const int* __restrict__ counts,
        float* __restrict__ newc) {
    int t = threadIdx.x;
    int half = t >> 7;                                  // wave-uniform (waves 0,1 vs 2,3)
    int tt = t & 127;
    const float4* c4 = (const float4*)centers;
    float4* n4 = (float4*)newc;
    for (int base = blockIdx.x * 8; base < C_N; base += gridDim.x * 8) {
        int row[4], cnt[4];
        float4 cv[4];
#pragma unroll
        for (int k = 0; k < 4; ++k) row[k] = base + 2 * k + half;
#pragma unroll
        for (int k = 0; k < 4; ++k) cnt[k] = counts[row[k]];      // wave-uniform
#pragma unroll
        for (int k = 0; k < 4; ++k) cv[k] = c4[(size_t)row[k] * 128 + tt];
#pragma unroll
        for (int k = 0; k < 4; ++k) {
            int n = cnt[k];
            float4 res;
            if (n == 0) {
                res = cv[k];                            // fast path: pure copy
            } else {                                    // rare: <=256 of 50000 rows
                int c = row[k];
                float4 sx = make_float4(0.f, 0.f, 0.f, 0.f);
                for (int b = 0; b < B_N; ++b) {
                    if (labels[b] == c) {               // wave-uniform branch
                        float4 xv = ((const float4*)(x + (size_t)b * D_N))[tt];
                        sx.x += xv.x; sx.y += xv.y; sx.z += xv.z; sx.w += xv.w;
                    }
                }
                float inv = 1.0f / (float)(n + 1);
                float ac = 1.0f - ALPHA * (float)n * inv;
                float bc = ALPHA * inv;
                res.x = cv[k].x * ac + sx.x * bc;
                res.y = cv[k].y * ac + sx.y * bc;
                res.z = cv[k].z * ac + sx.z * bc;
                res.w = cv[k].w * ac + sx.w * bc;
            }
            n4[(size_t)row[k] * 128 + tt] = res;
        }
    }
}

extern "C" void kernel_launch(void* const* d_in, const int* in_sizes, int n_in,
                              void* d_out, int out_size, void* d_ws, size_t ws_size,
                              hipStream_t stream) {
    const float* x       = (const float*)d_in[0];   // [B, D]
    const float* onehot  = (const float*)d_in[1];   // [B, C]
    const float* centers = (const float*)d_in[2];   // [C, D]
    float* out    = (float*)d_out;
    float* result = out;                            // [B, 1] -> 256 floats
    float* newc   = out + B_N;                      // [C, D]

    int* counts = (int*)d_ws;                       // C ints (200 KB)
    int* labels = counts + C_N;                     // B ints

    hipMemsetAsync(counts, 0, C_N * sizeof(int), stream);

    find_labels<<<(B_N * C_N / 4) / 1024, 256, 0, stream>>>(onehot, labels, counts);
    sq_dist<<<B_N, 128, 0, stream>>>(x, centers, labels, result);
    update_centers<<<2048, 256, 0, stream>>>(x, centers, labels, counts, newc);
}